// Round 5
// baseline (1291.775 us; speedup 1.0000x reference)
//
#include <hip/hip_runtime.h>
#include <cstdint>

#define EE 200000
#define NN 20000

// pool layout: P0 [3][NN][32] | P1 [4][NN][3][32] | P2 [4][NN][5][32]
#define P1_OFF (3u * NN * 32u)                     // 1,920,000
#define P2_OFF (P1_OFF + 4u * NN * 3u * 32u)       // 9,600,000
#define POOL_FLOATS (P2_OFF + 4u * NN * 5u * 32u)  // 22,400,000

__device__ float g_pool[POOL_FLOATS];              // 89.6 MB static device global

// ===========================================================================
// Compile-time CG constants: constexpr numpy default_rng(42) reproduction.
// ===========================================================================
namespace cg {

constexpr double LN2 = 0.69314718055994530941723212145818;
constexpr double PI_ = 3.1415926535897932384626433832795;

constexpr double c_sqrt(double x) {
    if (x <= 0.0) return 0.0;
    double g = x >= 1.0 ? x : 1.0;
    for (int i = 0; i < 64; i++) {
        double n = 0.5 * (g + x / g);
        if (n == g) break;
        g = n;
    }
    return g;
}

constexpr double c_exp(double x) {  // x in ~[-14, 1]
    double t = x / LN2;
    int n = (int)(t >= 0 ? t + 0.5 : t - 0.5);
    double r = x - (double)n * LN2;
    double s = 1.0, term = 1.0;
    for (int i = 1; i <= 26; i++) { term = term * r / (double)i; s += term; }
    double p = 1.0;
    int m = n < 0 ? -n : n;
    for (int i = 0; i < m; i++) p *= 2.0;
    return n >= 0 ? s * p : s / p;
}

constexpr double c_log(double x) {  // x > 0
    int n = 0;
    double m = x;
    while (m > 1.3333333333333333) { m *= 0.5; n++; }
    while (m < 0.6666666666666666) { m *= 2.0; n--; }
    double t = (m - 1.0) / (m + 1.0);     // |t| <= 0.2
    double t2 = t * t, s = 0.0;
    for (int k = 34; k >= 0; k--) s = s * t2 + 1.0 / (double)(2 * k + 1);
    return 2.0 * t * s + (double)n * LN2;
}

// erfc(z) = e^{-z^2}/sqrt(pi) * 1/(z+ (1/2)/(z+ 1/(z+ (3/2)/(z+ ...))))  [A&S 7.1.14]
constexpr double c_erfc(double z) {
    double t = 0.0;
    for (int k = 160; k >= 1; k--) t = ((double)k * 0.5) / (z + t);
    return c_exp(-z * z) / c_sqrt(PI_) / (z + t);
}

constexpr uint32_t hashmix(uint32_t v, uint32_t& hc) {
    v ^= hc; hc *= 0x931e8875u; v *= hc; v ^= v >> 16; return v;
}
// numpy bit_generator.pyx mix(): x*MIX_MULT_L - y*MIX_MULT_R, then xor-shift.
// (Round 1-4 bug: used XOR instead of subtraction.)
constexpr uint32_t mix2(uint32_t x, uint32_t y) {
    uint32_t r = x * 0xca01f9ddu - y * 0x4973f715u;
    r ^= r >> 16;
    return r;
}
constexpr uint64_t umulhi(uint64_t a, uint64_t b) {
    uint64_t al = a & 0xffffffffull, ah = a >> 32, bl = b & 0xffffffffull, bh = b >> 32;
    uint64_t ll = al * bl, lh = al * bh, hl = ah * bl, hh = ah * bh;
    uint64_t mid = (ll >> 32) + (lh & 0xffffffffull) + (hl & 0xffffffffull);
    return hh + (lh >> 32) + (hl >> 32) + (mid >> 32);
}

struct Rng { uint64_t slo, shi, ilo, ihi; };

constexpr uint64_t pcg_next(Rng& g) {
    constexpr uint64_t mlo = 0x4385df649fccf645ull, mhi = 0x2360ed051fc65da4ull;
    uint64_t rlo = g.slo * mlo;
    uint64_t rhi = umulhi(g.slo, mlo) + g.slo * mhi + g.shi * mlo;
    uint64_t nlo = rlo + g.ilo;
    uint64_t nhi = rhi + g.ihi + (nlo < rlo ? 1u : 0u);
    g.slo = nlo; g.shi = nhi;
    uint64_t x = nhi ^ nlo;
    unsigned rot = (unsigned)(nhi >> 58);
    return (x >> rot) | (x << ((64u - rot) & 63u));
}
constexpr double pcg_dbl(Rng& g) {
    return (double)(pcg_next(g) >> 11) * (1.0 / 9007199254740992.0);
}

constexpr Rng seed42() {
    uint32_t hc = 0x43b0d7e5u;                       // INIT_A
    uint32_t pl[4] = {};
    pl[0] = hashmix(42u, hc);
    for (int i = 1; i < 4; i++) pl[i] = hashmix(0u, hc);
    for (int s = 0; s < 4; s++)
        for (int d = 0; d < 4; d++)
            if (s != d) pl[d] = mix2(pl[d], hashmix(pl[s], hc));
    uint32_t gh = 0x8b51f9ddu;                       // INIT_B; MULT_B inside
    uint32_t w[8] = {};
    for (int i = 0; i < 8; i++) {
        uint32_t dv = pl[i & 3];
        dv ^= gh; gh *= 0x58f38dedu; dv *= gh; dv ^= dv >> 16; w[i] = dv;
    }
    uint64_t st_hi = (uint64_t)w[0] | ((uint64_t)w[1] << 32);   // seed[0] = HIGH
    uint64_t st_lo = (uint64_t)w[2] | ((uint64_t)w[3] << 32);
    uint64_t sq_hi = (uint64_t)w[4] | ((uint64_t)w[5] << 32);
    uint64_t sq_lo = (uint64_t)w[6] | ((uint64_t)w[7] << 32);
    Rng g{};
    g.ihi = (sq_hi << 1) | (sq_lo >> 63);            // inc = (initseq<<1)|1
    g.ilo = (sq_lo << 1) | 1ull;
    // srandom: state=0; step -> state=inc; state+=initstate; step.
    uint64_t alo = g.ilo + st_lo;
    uint64_t ahi = g.ihi + st_hi + (alo < g.ilo ? 1u : 0u);
    constexpr uint64_t mlo = 0x4385df649fccf645ull, mhi = 0x2360ed051fc65da4ull;
    uint64_t rlo = alo * mlo;
    uint64_t rhi = umulhi(alo, mlo) + alo * mhi + ahi * mlo;
    g.slo = rlo + g.ilo;
    g.shi = rhi + g.ihi + (g.slo < rlo ? 1u : 0u);
    return g;
}

struct CGTab { float v[363]; };

constexpr CGTab gen_cg() {
    constexpr double R = 3.6541528853610087963519472518;
    constexpr double INVR = 0.27366123732975827203338247596;   // 1/R (numpy literal)
    constexpr double M52 = 4503599627370496.0;                 // 2^52

    // ---- ziggurat tables (numpy ziggurat_constants.h recursion) ----
    double wi[256] = {}, fi[256] = {};
    uint64_t ki[256] = {};
    {
        double f = c_exp(-0.5 * R * R);
        double v = R * f + c_sqrt(PI_ / 2.0) * c_erfc(R / c_sqrt(2.0));
        double xs[256] = {}, fs[256] = {};
        xs[255] = R; fs[255] = f;
        for (int i = 255; i >= 2; i--) {
            double fp = fs[i] + v / xs[i];
            xs[i - 1] = c_sqrt(-2.0 * c_log(fp));
            fs[i - 1] = fp;
        }
        xs[0] = 0.0; fs[0] = 1.0;
        wi[0] = (v / f) / M52;
        fi[0] = 1.0;
        ki[0] = (uint64_t)((R * f / v) * M52);
        for (int i = 1; i < 256; i++) {
            wi[i] = xs[i] / M52;
            fi[i] = fs[i];
            ki[i] = (uint64_t)((xs[i - 1] / xs[i]) * M52);
        }
    }

    Rng g = seed42();
    CGTab out{};
    // numpy dict generation order (l1,l2,L ascending); dst<0 = odd parity (discarded)
    const int cnts[15] = {1, 9, 25, 9, 9, 27, 45, 45, 75, 25, 45, 75, 25, 75, 125};
    const int dsts[15] = {0, 35, 143, 44, 1, -1, 168, 53, -1, 213, 98, -1, 10, -1, 238};

    for (int ri = 0; ri < 15; ri++) {
        for (int i = 0; i < cnts[ri]; i++) {
            double xv = 0.0;
            for (;;) {
                uint64_t r = pcg_next(g);
                int idx = (int)(r & 0xff);
                r >>= 8;
                int sign = (int)(r & 1);
                uint64_t rabs = (r >> 1) & 0x000fffffffffffffull;
                double x = (double)rabs * wi[idx];
                if (sign) x = -x;
                if (rabs < ki[idx]) { xv = x; break; }
                if (idx == 0) {
                    double xx = 0.0, yy = 0.0;
                    do {
                        // log1p(-u) == log(1-u); 1-u exact (Sterbenz / representable)
                        xx = -INVR * c_log(1.0 - pcg_dbl(g));
                        yy = -c_log(1.0 - pcg_dbl(g));
                    } while (yy + yy <= xx * xx);
                    xv = ((rabs >> 8) & 1) ? -(R + xx) : (R + xx);
                    break;
                } else {
                    if ((fi[idx - 1] - fi[idx]) * pcg_dbl(g) + fi[idx] < c_exp(-0.5 * x * x)) {
                        xv = x; break;
                    }
                }
            }
            if (dsts[ri] >= 0) out.v[dsts[ri] + i] = (float)(xv * 0.3);
        }
    }
    return out;
}

} // namespace cg

constexpr cg::CGTab CG_TAB = cg::gen_cg();   // evaluated at compile time; literals below

// ===========================================================================
// Kernels
// ===========================================================================

__global__ __launch_bounds__(256) void zk() {
    size_t i = (size_t)blockIdx.x * 256 + threadIdx.x;   // one float4 per thread
    float4* p4 = (float4*)g_pool;
    p4[i] = make_float4(0.f, 0.f, 0.f, 0.f);
}

template <int A, int B, int MM, int OFF>
__device__ __forceinline__ void combo(const float* va, const float* fb, float* res) {
#pragma unroll
    for (int m = 0; m < MM; m++) res[m] = 0.f;
#pragma unroll
    for (int a = 0; a < A; a++) {
#pragma unroll
        for (int b = 0; b < B; b++) {
            float p = va[a] * fb[b];
#pragma unroll
            for (int m = 0; m < MM; m++)
                res[m] = fmaf(p, CG_TAB.v[OFF + (a * B + b) * MM + m], res[m]);
        }
    }
}

__global__ __launch_bounds__(256) void ek(
    const float* __restrict__ radial,
    const float* __restrict__ sh0, const float* __restrict__ sh1, const float* __restrict__ sh2,
    const float* __restrict__ feat0, const float* __restrict__ feat1, const float* __restrict__ feat2,
    const int* __restrict__ centers, const int* __restrict__ neighbors)
{
    int t = blockIdx.x * 256 + threadIdx.x;
    int e = t >> 5;
    if (e >= EE) return;
    int k = t & 31;

    int cen = centers[e];
    int nb  = neighbors[e];

    float r0 = radial[(size_t)e * 32 + k];
    float r1 = radial[((size_t)EE + e) * 32 + k];
    float r2 = radial[((size_t)2 * EE + e) * 32 + k];

    float v0[1] = { sh0[e] * r0 };
    float v1[3], v2[5];
#pragma unroll
    for (int a = 0; a < 3; a++) v1[a] = sh1[(size_t)e * 3 + a] * r1;
#pragma unroll
    for (int a = 0; a < 5; a++) v2[a] = sh2[(size_t)e * 5 + a] * r2;

    float f0[1] = { feat0[(size_t)nb * 32 + k] };
    float f1[3], f2[5];
#pragma unroll
    for (int b = 0; b < 3; b++) f1[b] = feat1[((size_t)nb * 3 + b) * 32 + k];
#pragma unroll
    for (int b = 0; b < 5; b++) f2[b] = feat2[((size_t)nb * 5 + b) * 32 + k];

    float* P0 = g_pool;
    float* P1 = g_pool + P1_OFF;
    float* P2 = g_pool + P2_OFF;

    float res[5];

    // ---- L = 0: combos (0,0)@0, (1,1)@1, (2,2)@10 ----
    combo<1, 1, 1, 0>(v0, f0, res);
    atomicAdd(&P0[((size_t)0 * NN + cen) * 32 + k], res[0]);
    combo<3, 3, 1, 1>(v1, f1, res);
    atomicAdd(&P0[((size_t)1 * NN + cen) * 32 + k], res[0]);
    combo<5, 5, 1, 10>(v2, f2, res);
    atomicAdd(&P0[((size_t)2 * NN + cen) * 32 + k], res[0]);

    // ---- L = 1: combos (0,1)@35, (1,0)@44, (1,2)@53, (2,1)@98 ----
    combo<1, 3, 3, 35>(v0, f1, res);
#pragma unroll
    for (int m = 0; m < 3; m++)
        atomicAdd(&P1[(((size_t)0 * NN + cen) * 3 + m) * 32 + k], res[m]);
    combo<3, 1, 3, 44>(v1, f0, res);
#pragma unroll
    for (int m = 0; m < 3; m++)
        atomicAdd(&P1[(((size_t)1 * NN + cen) * 3 + m) * 32 + k], res[m]);
    combo<3, 5, 3, 53>(v1, f2, res);
#pragma unroll
    for (int m = 0; m < 3; m++)
        atomicAdd(&P1[(((size_t)2 * NN + cen) * 3 + m) * 32 + k], res[m]);
    combo<5, 3, 3, 98>(v2, f1, res);
#pragma unroll
    for (int m = 0; m < 3; m++)
        atomicAdd(&P1[(((size_t)3 * NN + cen) * 3 + m) * 32 + k], res[m]);

    // ---- L = 2: combos (0,2)@143, (1,1)@168, (2,0)@213, (2,2)@238 ----
    combo<1, 5, 5, 143>(v0, f2, res);
#pragma unroll
    for (int m = 0; m < 5; m++)
        atomicAdd(&P2[(((size_t)0 * NN + cen) * 5 + m) * 32 + k], res[m]);
    combo<3, 3, 5, 168>(v1, f1, res);
#pragma unroll
    for (int m = 0; m < 5; m++)
        atomicAdd(&P2[(((size_t)1 * NN + cen) * 5 + m) * 32 + k], res[m]);
    combo<5, 1, 5, 213>(v2, f0, res);
#pragma unroll
    for (int m = 0; m < 5; m++)
        atomicAdd(&P2[(((size_t)2 * NN + cen) * 5 + m) * 32 + k], res[m]);
    combo<5, 5, 5, 238>(v2, f2, res);
#pragma unroll
    for (int m = 0; m < 5; m++)
        atomicAdd(&P2[(((size_t)3 * NN + cen) * 5 + m) * 32 + k], res[m]);
}

__global__ __launch_bounds__(256) void ak(
    const float* __restrict__ feat0, const float* __restrict__ feat1, const float* __restrict__ feat2,
    const float* __restrict__ W0, const float* __restrict__ b0,
    const float* __restrict__ W1, const float* __restrict__ b1,
    const float* __restrict__ W2, const float* __restrict__ b2,
    float* __restrict__ out)
{
    int t = blockIdx.x * 256 + threadIdx.x;
    int n = t >> 5;
    if (n >= NN) return;
    int kp = t & 31;

    const float* P0 = g_pool;
    const float* P1 = g_pool + P1_OFF;
    const float* P2 = g_pool + P2_OFF;

    float a0 = 0.f;
    float a1[3] = {0.f, 0.f, 0.f};
    float a2[5] = {0.f, 0.f, 0.f, 0.f, 0.f};

#pragma unroll
    for (int c = 0; c < 3; c++) {
        const float* pr = &P0[((size_t)c * NN + n) * 32];
        const float* wc = &W0[(size_t)c * 32 * 32 + kp];
#pragma unroll 8
        for (int kk = 0; kk < 32; kk++)
            a0 = fmaf(pr[kk], wc[(size_t)kk * 32], a0);
    }
#pragma unroll
    for (int c = 0; c < 4; c++) {
        const float* pr = &P1[((size_t)c * NN + n) * 3 * 32];
        const float* wc = &W1[(size_t)c * 32 * 32 + kp];
#pragma unroll 4
        for (int kk = 0; kk < 32; kk++) {
            float w = wc[(size_t)kk * 32];
            a1[0] = fmaf(pr[0 * 32 + kk], w, a1[0]);
            a1[1] = fmaf(pr[1 * 32 + kk], w, a1[1]);
            a1[2] = fmaf(pr[2 * 32 + kk], w, a1[2]);
        }
    }
#pragma unroll
    for (int c = 0; c < 4; c++) {
        const float* pr = &P2[((size_t)c * NN + n) * 5 * 32];
        const float* wc = &W2[(size_t)c * 32 * 32 + kp];
#pragma unroll 4
        for (int kk = 0; kk < 32; kk++) {
            float w = wc[(size_t)kk * 32];
#pragma unroll
            for (int m = 0; m < 5; m++)
                a2[m] = fmaf(pr[m * 32 + kk], w, a2[m]);
        }
    }

    out[(size_t)n * 32 + kp] = 0.1f * (a0 + b0[kp]) + feat0[(size_t)n * 32 + kp];
#pragma unroll
    for (int m = 0; m < 3; m++)
        out[640000 + ((size_t)n * 3 + m) * 32 + kp] =
            0.1f * (a1[m] + b1[kp]) + feat1[((size_t)n * 3 + m) * 32 + kp];
#pragma unroll
    for (int m = 0; m < 5; m++)
        out[2560000 + ((size_t)n * 5 + m) * 32 + kp] =
            0.1f * (a2[m] + b2[kp]) + feat2[((size_t)n * 5 + m) * 32 + kp];
}

// ===========================================================================

extern "C" void kernel_launch(void* const* d_in, const int* in_sizes, int n_in,
                              void* d_out, int out_size, void* d_ws, size_t ws_size,
                              hipStream_t stream) {
    const float* radial = (const float*)d_in[0];
    const float* sh0    = (const float*)d_in[1];
    const float* sh1    = (const float*)d_in[2];
    const float* sh2    = (const float*)d_in[3];
    const float* feat0  = (const float*)d_in[4];
    const float* feat1  = (const float*)d_in[5];
    const float* feat2  = (const float*)d_in[6];
    const float* W0     = (const float*)d_in[7];
    const float* b0     = (const float*)d_in[8];
    const float* W1     = (const float*)d_in[9];
    const float* b1     = (const float*)d_in[10];
    const float* W2     = (const float*)d_in[11];
    const float* b2     = (const float*)d_in[12];
    const int* centers   = (const int*)d_in[13];
    const int* neighbors = (const int*)d_in[14];

    zk<<<POOL_FLOATS / 4 / 256, 256, 0, stream>>>();                 // 21875 blocks

    ek<<<(EE * 32) / 256, 256, 0, stream>>>(radial, sh0, sh1, sh2,   // 25000 blocks
                                            feat0, feat1, feat2, centers, neighbors);

    ak<<<(NN * 32) / 256, 256, 0, stream>>>(feat0, feat1, feat2,     // 2500 blocks
                                            W0, b0, W1, b1, W2, b2, (float*)d_out);
}

// Round 7
// 434.051 us; speedup vs baseline: 2.9761x; 2.9761x over previous
//
#include <hip/hip_runtime.h>
#include <cstdint>

#define EE 200000
#define NN 20000

// ===========================================================================
// Compile-time CG constants: constexpr numpy default_rng(42) reproduction.
// (Verified: round 5 passed with absmax 1.56e-2.)
// ===========================================================================
namespace cg {

constexpr double LN2 = 0.69314718055994530941723212145818;
constexpr double PI_ = 3.1415926535897932384626433832795;

constexpr double c_sqrt(double x) {
    if (x <= 0.0) return 0.0;
    double g = x >= 1.0 ? x : 1.0;
    for (int i = 0; i < 64; i++) {
        double n = 0.5 * (g + x / g);
        if (n == g) break;
        g = n;
    }
    return g;
}

constexpr double c_exp(double x) {  // x in ~[-14, 1]
    double t = x / LN2;
    int n = (int)(t >= 0 ? t + 0.5 : t - 0.5);
    double r = x - (double)n * LN2;
    double s = 1.0, term = 1.0;
    for (int i = 1; i <= 26; i++) { term = term * r / (double)i; s += term; }
    double p = 1.0;
    int m = n < 0 ? -n : n;
    for (int i = 0; i < m; i++) p *= 2.0;
    return n >= 0 ? s * p : s / p;
}

constexpr double c_log(double x) {  // x > 0
    int n = 0;
    double m = x;
    while (m > 1.3333333333333333) { m *= 0.5; n++; }
    while (m < 0.6666666666666666) { m *= 2.0; n--; }
    double t = (m - 1.0) / (m + 1.0);     // |t| <= 0.2
    double t2 = t * t, s = 0.0;
    for (int k = 34; k >= 0; k--) s = s * t2 + 1.0 / (double)(2 * k + 1);
    return 2.0 * t * s + (double)n * LN2;
}

// erfc(z) = e^{-z^2}/sqrt(pi) * 1/(z+ (1/2)/(z+ 1/(z+ (3/2)/(z+ ...))))  [A&S 7.1.14]
constexpr double c_erfc(double z) {
    double t = 0.0;
    for (int k = 160; k >= 1; k--) t = ((double)k * 0.5) / (z + t);
    return c_exp(-z * z) / c_sqrt(PI_) / (z + t);
}

constexpr uint32_t hashmix(uint32_t v, uint32_t& hc) {
    v ^= hc; hc *= 0x931e8875u; v *= hc; v ^= v >> 16; return v;
}
// numpy bit_generator.pyx mix(): x*MIX_MULT_L - y*MIX_MULT_R, then xor-shift.
constexpr uint32_t mix2(uint32_t x, uint32_t y) {
    uint32_t r = x * 0xca01f9ddu - y * 0x4973f715u;
    r ^= r >> 16;
    return r;
}
constexpr uint64_t umulhi(uint64_t a, uint64_t b) {
    uint64_t al = a & 0xffffffffull, ah = a >> 32, bl = b & 0xffffffffull, bh = b >> 32;
    uint64_t ll = al * bl, lh = al * bh, hl = ah * bl, hh = ah * bh;
    uint64_t mid = (ll >> 32) + (lh & 0xffffffffull) + (hl & 0xffffffffull);
    return hh + (lh >> 32) + (hl >> 32) + (mid >> 32);
}

struct Rng { uint64_t slo, shi, ilo, ihi; };

constexpr uint64_t pcg_next(Rng& g) {
    constexpr uint64_t mlo = 0x4385df649fccf645ull, mhi = 0x2360ed051fc65da4ull;
    uint64_t rlo = g.slo * mlo;
    uint64_t rhi = umulhi(g.slo, mlo) + g.slo * mhi + g.shi * mlo;
    uint64_t nlo = rlo + g.ilo;
    uint64_t nhi = rhi + g.ihi + (nlo < rlo ? 1u : 0u);
    g.slo = nlo; g.shi = nhi;
    uint64_t x = nhi ^ nlo;
    unsigned rot = (unsigned)(nhi >> 58);
    return (x >> rot) | (x << ((64u - rot) & 63u));
}
constexpr double pcg_dbl(Rng& g) {
    return (double)(pcg_next(g) >> 11) * (1.0 / 9007199254740992.0);
}

constexpr Rng seed42() {
    uint32_t hc = 0x43b0d7e5u;                       // INIT_A
    uint32_t pl[4] = {};
    pl[0] = hashmix(42u, hc);
    for (int i = 1; i < 4; i++) pl[i] = hashmix(0u, hc);
    for (int s = 0; s < 4; s++)
        for (int d = 0; d < 4; d++)
            if (s != d) pl[d] = mix2(pl[d], hashmix(pl[s], hc));
    uint32_t gh = 0x8b51f9ddu;                       // INIT_B; MULT_B inside
    uint32_t w[8] = {};
    for (int i = 0; i < 8; i++) {
        uint32_t dv = pl[i & 3];
        dv ^= gh; gh *= 0x58f38dedu; dv *= gh; dv ^= dv >> 16; w[i] = dv;
    }
    uint64_t st_hi = (uint64_t)w[0] | ((uint64_t)w[1] << 32);   // seed[0] = HIGH
    uint64_t st_lo = (uint64_t)w[2] | ((uint64_t)w[3] << 32);
    uint64_t sq_hi = (uint64_t)w[4] | ((uint64_t)w[5] << 32);
    uint64_t sq_lo = (uint64_t)w[6] | ((uint64_t)w[7] << 32);
    Rng g{};
    g.ihi = (sq_hi << 1) | (sq_lo >> 63);            // inc = (initseq<<1)|1
    g.ilo = (sq_lo << 1) | 1ull;
    // srandom: state=0; step -> state=inc; state+=initstate; step.
    uint64_t alo = g.ilo + st_lo;
    uint64_t ahi = g.ihi + st_hi + (alo < g.ilo ? 1u : 0u);
    constexpr uint64_t mlo = 0x4385df649fccf645ull, mhi = 0x2360ed051fc65da4ull;
    uint64_t rlo = alo * mlo;
    uint64_t rhi = umulhi(alo, mlo) + alo * mhi + ahi * mlo;
    g.slo = rlo + g.ilo;
    g.shi = rhi + g.ihi + (g.slo < rlo ? 1u : 0u);
    return g;
}

struct CGTab { float v[363]; };

constexpr CGTab gen_cg() {
    constexpr double R = 3.6541528853610087963519472518;
    constexpr double INVR = 0.27366123732975827203338247596;   // 1/R (numpy literal)
    constexpr double M52 = 4503599627370496.0;                 // 2^52

    double wi[256] = {}, fi[256] = {};
    uint64_t ki[256] = {};
    {
        double f = c_exp(-0.5 * R * R);
        double v = R * f + c_sqrt(PI_ / 2.0) * c_erfc(R / c_sqrt(2.0));
        double xs[256] = {}, fs[256] = {};
        xs[255] = R; fs[255] = f;
        for (int i = 255; i >= 2; i--) {
            double fp = fs[i] + v / xs[i];
            xs[i - 1] = c_sqrt(-2.0 * c_log(fp));
            fs[i - 1] = fp;
        }
        xs[0] = 0.0; fs[0] = 1.0;
        wi[0] = (v / f) / M52;
        fi[0] = 1.0;
        ki[0] = (uint64_t)((R * f / v) * M52);
        for (int i = 1; i < 256; i++) {
            wi[i] = xs[i] / M52;
            fi[i] = fs[i];
            ki[i] = (uint64_t)((xs[i - 1] / xs[i]) * M52);
        }
    }

    Rng g = seed42();
    CGTab out{};
    // numpy dict generation order (l1,l2,L ascending); dst<0 = odd parity (discarded)
    const int cnts[15] = {1, 9, 25, 9, 9, 27, 45, 45, 75, 25, 45, 75, 25, 75, 125};
    const int dsts[15] = {0, 35, 143, 44, 1, -1, 168, 53, -1, 213, 98, -1, 10, -1, 238};

    for (int ri = 0; ri < 15; ri++) {
        for (int i = 0; i < cnts[ri]; i++) {
            double xv = 0.0;
            for (;;) {
                uint64_t r = pcg_next(g);
                int idx = (int)(r & 0xff);
                r >>= 8;
                int sign = (int)(r & 1);
                uint64_t rabs = (r >> 1) & 0x000fffffffffffffull;
                double x = (double)rabs * wi[idx];
                if (sign) x = -x;
                if (rabs < ki[idx]) { xv = x; break; }
                if (idx == 0) {
                    double xx = 0.0, yy = 0.0;
                    do {
                        xx = -INVR * c_log(1.0 - pcg_dbl(g));
                        yy = -c_log(1.0 - pcg_dbl(g));
                    } while (yy + yy <= xx * xx);
                    xv = ((rabs >> 8) & 1) ? -(R + xx) : (R + xx);
                    break;
                } else {
                    if ((fi[idx - 1] - fi[idx]) * pcg_dbl(g) + fi[idx] < c_exp(-0.5 * x * x)) {
                        xv = x; break;
                    }
                }
            }
            if (dsts[ri] >= 0) out.v[dsts[ri] + i] = (float)(xv * 0.3);
        }
    }
    return out;
}

} // namespace cg

constexpr cg::CGTab CG_TAB = cg::gen_cg();

// ===========================================================================
// CSR-by-center scratch (static device globals; fully rewritten every call)
// ===========================================================================
__device__ int g_cnt[NN];
__device__ int g_row[NN + 1];
__device__ int g_cur[NN];
__device__ int g_eidx[EE];

__global__ __launch_bounds__(256) void zcnt() {
    int i = blockIdx.x * 256 + threadIdx.x;
    if (i < NN) g_cnt[i] = 0;
}

__global__ __launch_bounds__(256) void hist(const int* __restrict__ centers) {
    int e = blockIdx.x * 256 + threadIdx.x;
    if (e < EE) atomicAdd(&g_cnt[centers[e]], 1);
}

// single-block scan: 1024 threads x 20-element chunks (covers 20480 >= NN)
__global__ __launch_bounds__(1024) void scan() {
    __shared__ int part[1024];
    int t = threadIdx.x;
    int base = t * 20;
    int s = 0;
    for (int i = 0; i < 20; i++) {
        int idx = base + i;
        if (idx < NN) s += g_cnt[idx];
    }
    part[t] = s;
    __syncthreads();
    for (int off = 1; off < 1024; off <<= 1) {
        int v = (t >= off) ? part[t - off] : 0;
        __syncthreads();
        part[t] += v;
        __syncthreads();
    }
    int run = (t > 0) ? part[t - 1] : 0;
    for (int i = 0; i < 20; i++) {
        int idx = base + i;
        if (idx < NN) {
            g_row[idx] = run;
            g_cur[idx] = run;
            run += g_cnt[idx];
        }
    }
    if (t == 0) g_row[NN] = EE;
}

__global__ __launch_bounds__(256) void scat(const int* __restrict__ centers) {
    int e = blockIdx.x * 256 + threadIdx.x;
    if (e < EE) {
        int pos = atomicAdd(&g_cur[centers[e]], 1);
        g_eidx[pos] = e;
    }
}

// ===========================================================================
// Fused kernel: per (atom, k) gather edges -> CG contraction in registers ->
// LDS k-exchange -> linear + bias + scale + residual -> out.
// acc layout (35): [0..2]=L0 c; [3..14]=L1 c*3+m; [15..34]=L2 c*5+m
// ===========================================================================
template <int A, int B, int MM, int OFF>
__device__ __forceinline__ void combo_acc(const float* va, const float* fb, float* accp) {
#pragma unroll
    for (int a = 0; a < A; a++) {
#pragma unroll
        for (int b = 0; b < B; b++) {
            float p = va[a] * fb[b];
#pragma unroll
            for (int m = 0; m < MM; m++)
                accp[m] = fmaf(p, CG_TAB.v[OFF + (a * B + b) * MM + m], accp[m]);
        }
    }
}

__global__ __launch_bounds__(256) void mk(
    const float* __restrict__ radial,
    const float* __restrict__ sh0, const float* __restrict__ sh1, const float* __restrict__ sh2,
    const float* __restrict__ feat0, const float* __restrict__ feat1, const float* __restrict__ feat2,
    const float* __restrict__ W0, const float* __restrict__ b0,
    const float* __restrict__ W1, const float* __restrict__ b1,
    const float* __restrict__ W2, const float* __restrict__ b2,
    const int* __restrict__ neighbors,
    float* __restrict__ out)
{
    __shared__ float lds[8 * 35 * 32];       // 35,840 B -> 4 blocks/CU
    int tid = threadIdx.x;
    int a = tid >> 5;                        // local atom 0..7
    int k = tid & 31;
    int n = blockIdx.x * 8 + a;              // grid exactly NN/8 -> n < NN

    float acc[35];
#pragma unroll
    for (int i = 0; i < 35; i++) acc[i] = 0.f;

    int jb = g_row[n], je = g_row[n + 1];
    for (int j = jb; j < je; ++j) {
        int e = g_eidx[j];
        int nb = neighbors[e];

        float r0 = radial[(size_t)e * 32 + k];
        float r1 = radial[((size_t)EE + e) * 32 + k];
        float r2 = radial[((size_t)2 * EE + e) * 32 + k];

        float v0[1] = { sh0[e] * r0 };
        float v1[3], v2[5];
#pragma unroll
        for (int q = 0; q < 3; q++) v1[q] = sh1[(size_t)e * 3 + q] * r1;
#pragma unroll
        for (int q = 0; q < 5; q++) v2[q] = sh2[(size_t)e * 5 + q] * r2;

        float f0[1] = { feat0[(size_t)nb * 32 + k] };
        float f1[3], f2[5];
#pragma unroll
        for (int q = 0; q < 3; q++) f1[q] = feat1[((size_t)nb * 3 + q) * 32 + k];
#pragma unroll
        for (int q = 0; q < 5; q++) f2[q] = feat2[((size_t)nb * 5 + q) * 32 + k];

        // L0
        combo_acc<1, 1, 1, 0>(v0, f0, &acc[0]);
        combo_acc<3, 3, 1, 1>(v1, f1, &acc[1]);
        combo_acc<5, 5, 1, 10>(v2, f2, &acc[2]);
        // L1
        combo_acc<1, 3, 3, 35>(v0, f1, &acc[3]);
        combo_acc<3, 1, 3, 44>(v1, f0, &acc[6]);
        combo_acc<3, 5, 3, 53>(v1, f2, &acc[9]);
        combo_acc<5, 3, 3, 98>(v2, f1, &acc[12]);
        // L2
        combo_acc<1, 5, 5, 143>(v0, f2, &acc[15]);
        combo_acc<3, 3, 5, 168>(v1, f1, &acc[20]);
        combo_acc<5, 1, 5, 213>(v2, f0, &acc[25]);
        combo_acc<5, 5, 5, 238>(v2, f2, &acc[30]);
    }

    // k-exchange through LDS (intra-32-lane-group only; no block barrier needed —
    // compiler inserts lgkmcnt before dependent ds_read)
    float* L = &lds[a * 35 * 32];
#pragma unroll
    for (int c = 0; c < 35; c++) L[c * 32 + k] = acc[c];
    __builtin_amdgcn_wave_barrier();   // scheduling fence (free)

    // ---- linear: comp = cat @ W + b ; out = 0.1*comp + feat ----
    float o0 = b0[k];
    float o1[3] = { b1[k], b1[k], b1[k] };
    float o2[5] = { b2[k], b2[k], b2[k], b2[k], b2[k] };

    // L0: rows c*32+kk, pooled at L[c*32+kk]
#pragma unroll
    for (int c = 0; c < 3; c++) {
        for (int kk = 0; kk < 32; kk += 4) {
            float4 p = *reinterpret_cast<const float4*>(&L[c * 32 + kk]);
            const float* w = &W0[(size_t)(c * 32 + kk) * 32 + k];
            o0 = fmaf(p.x, w[0], o0);
            o0 = fmaf(p.y, w[32], o0);
            o0 = fmaf(p.z, w[64], o0);
            o0 = fmaf(p.w, w[96], o0);
        }
    }
    // L1: rows c*32+kk, pooled at L[(3 + c*3 + m)*32 + kk]
#pragma unroll
    for (int c = 0; c < 4; c++) {
        for (int kk = 0; kk < 32; kk += 4) {
            float4 pm[3];
#pragma unroll
            for (int m = 0; m < 3; m++)
                pm[m] = *reinterpret_cast<const float4*>(&L[(3 + c * 3 + m) * 32 + kk]);
            const float* w = &W1[(size_t)(c * 32 + kk) * 32 + k];
            float w0 = w[0], w1 = w[32], w2 = w[64], w3 = w[96];
#pragma unroll
            for (int m = 0; m < 3; m++) {
                o1[m] = fmaf(pm[m].x, w0, o1[m]);
                o1[m] = fmaf(pm[m].y, w1, o1[m]);
                o1[m] = fmaf(pm[m].z, w2, o1[m]);
                o1[m] = fmaf(pm[m].w, w3, o1[m]);
            }
        }
    }
    // L2: rows c*32+kk, pooled at L[(15 + c*5 + m)*32 + kk]
#pragma unroll
    for (int c = 0; c < 4; c++) {
        for (int kk = 0; kk < 32; kk += 4) {
            float4 pm[5];
#pragma unroll
            for (int m = 0; m < 5; m++)
                pm[m] = *reinterpret_cast<const float4*>(&L[(15 + c * 5 + m) * 32 + kk]);
            const float* w = &W2[(size_t)(c * 32 + kk) * 32 + k];
            float w0 = w[0], w1 = w[32], w2 = w[64], w3 = w[96];
#pragma unroll
            for (int m = 0; m < 5; m++) {
                o2[m] = fmaf(pm[m].x, w0, o2[m]);
                o2[m] = fmaf(pm[m].y, w1, o2[m]);
                o2[m] = fmaf(pm[m].z, w2, o2[m]);
                o2[m] = fmaf(pm[m].w, w3, o2[m]);
            }
        }
    }

    out[(size_t)n * 32 + k] = 0.1f * o0 + feat0[(size_t)n * 32 + k];
#pragma unroll
    for (int m = 0; m < 3; m++)
        out[640000 + ((size_t)n * 3 + m) * 32 + k] =
            0.1f * o1[m] + feat1[((size_t)n * 3 + m) * 32 + k];
#pragma unroll
    for (int m = 0; m < 5; m++)
        out[2560000 + ((size_t)n * 5 + m) * 32 + k] =
            0.1f * o2[m] + feat2[((size_t)n * 5 + m) * 32 + k];
}

// ===========================================================================

extern "C" void kernel_launch(void* const* d_in, const int* in_sizes, int n_in,
                              void* d_out, int out_size, void* d_ws, size_t ws_size,
                              hipStream_t stream) {
    const float* radial = (const float*)d_in[0];
    const float* sh0    = (const float*)d_in[1];
    const float* sh1    = (const float*)d_in[2];
    const float* sh2    = (const float*)d_in[3];
    const float* feat0  = (const float*)d_in[4];
    const float* feat1  = (const float*)d_in[5];
    const float* feat2  = (const float*)d_in[6];
    const float* W0     = (const float*)d_in[7];
    const float* b0     = (const float*)d_in[8];
    const float* W1     = (const float*)d_in[9];
    const float* b1     = (const float*)d_in[10];
    const float* W2     = (const float*)d_in[11];
    const float* b2     = (const float*)d_in[12];
    const int* centers   = (const int*)d_in[13];
    const int* neighbors = (const int*)d_in[14];

    zcnt<<<(NN + 255) / 256, 256, 0, stream>>>();
    hist<<<(EE + 255) / 256, 256, 0, stream>>>(centers);
    scan<<<1, 1024, 0, stream>>>();
    scat<<<(EE + 255) / 256, 256, 0, stream>>>(centers);
    mk<<<NN / 8, 256, 0, stream>>>(radial, sh0, sh1, sh2,
                                   feat0, feat1, feat2,
                                   W0, b0, W1, b1, W2, b2,
                                   neighbors, (float*)d_out);
}